// Round 6
// baseline (1043.154 us; speedup 1.0000x reference)
//
#include <hip/hip_runtime.h>
#include <hip/hip_bf16.h>

// ---------------------------------------------------------------------------
// ArrowTransformer forward: B=2, S=1024, D=1024, H=16, HD=64, L=6, V=256
// Round 5: attn_main LDS diet (no K LDS buffer -> 37.4 KB, 4 blocks/CU),
// direct-from-global K fragments, barrier moved after G phase,
// QKV GEMM 64x128 tile (768 blocks, uniform 3/CU).
// ---------------------------------------------------------------------------

typedef __attribute__((ext_vector_type(8))) short  s8_t;
typedef __attribute__((ext_vector_type(4))) short  s4_t;
typedef __attribute__((ext_vector_type(8))) __bf16 bf8_t;
typedef __attribute__((ext_vector_type(4))) float  f4v;

static __device__ __forceinline__ short f2bf(float f) {
  union { float f; unsigned u; } a; a.f = f;
  unsigned u = a.u;
  u += 0x7fffu + ((u >> 16) & 1u);
  return (short)(u >> 16);
}
static __device__ __forceinline__ float bf2f(short s) {
  union { float f; unsigned u; } a;
  a.u = ((unsigned)(unsigned short)s) << 16;
  return a.f;
}
static __device__ __forceinline__ f4v mfma16(s8_t a, s8_t b, f4v c) {
  return __builtin_amdgcn_mfma_f32_16x16x32_bf16(
      __builtin_bit_cast(bf8_t, a), __builtin_bit_cast(bf8_t, b), c, 0, 0, 0);
}
static __device__ __forceinline__ void gld16(const short* g, short* l) {
  __builtin_amdgcn_global_load_lds(
      (const __attribute__((address_space(1))) void*)g,
      (__attribute__((address_space(3))) void*)l, 16, 0, 0);
}

// chunk table: heavy q-tiles first. nc(itile) = itile/4 + 1. chunk = 256 keys.
static __device__ const int IT_TAB[40] = {
  15,15,15,15, 14,14,14,14, 13,13,13,13, 12,12,12,12,
  11,11,11, 10,10,10, 9,9,9, 8,8,8,
  7,7, 6,6, 5,5, 4,4, 3, 2, 1, 0};
static __device__ const int CW_TAB[40] = {
  0,1,2,3, 0,1,2,3, 0,1,2,3, 0,1,2,3,
  0,1,2, 0,1,2, 0,1,2, 0,1,2,
  0,1, 0,1, 0,1, 0,1, 0, 0, 0, 0};

// ---------------------------------------------------------------------------
// Unified weight prep: all transposes (f32 -> bf16, [N][K] layout).
// ---------------------------------------------------------------------------
__global__ void prep_weights(
    const float* __restrict__ Wq, const float* __restrict__ Wk,
    const float* __restrict__ Wv, const float* __restrict__ Wo,
    const float* __restrict__ W1, const float* __restrict__ W2,
    const float* __restrict__ Wf,
    short* __restrict__ qkvT, short* __restrict__ WoT, short* __restrict__ W1T,
    short* __restrict__ W2T, short* __restrict__ WfT) {
  __shared__ float tile[32][33];
  int z = blockIdx.x;
  const float* in; short* out; int R, C; long outBS; int rowOff = 0;
  if (z < 18432) {
    R = 1024; C = 1024; outBS = (long)3072 * 1024; out = qkvT;
    if (z < 6144)       { in = Wq; }
    else if (z < 12288) { in = Wk; rowOff = 1024; z -= 6144; }
    else                { in = Wv; rowOff = 2048; z -= 12288; }
  } else if (z < 24576) { in = Wo; out = WoT; R = 1024; C = 1024; outBS = (long)1024 * 1024; z -= 18432; }
  else if (z < 27648)   { in = W1; out = W1T; R = 1024; C = 512;  outBS = (long)512 * 1024;  z -= 24576; }
  else if (z < 30720)   { in = W2; out = W2T; R = 512;  C = 1024; outBS = (long)1024 * 512;  z -= 27648; }
  else                  { in = Wf; out = WfT; R = 1024; C = 256;  outBS = 0;                 z -= 30720; }
  const int nx = C >> 5, ny = R >> 5;
  const int per = nx * ny;
  const int l = z / per, rem = z % per;
  const int cx = rem % nx, cy = rem / nx;
  in += (long)l * R * C;
  out += (long)l * outBS + (long)rowOff * R;
  const int c0 = cx * 32, r0 = cy * 32;
  const int tx = threadIdx.x, ty = threadIdx.y;
#pragma unroll
  for (int i = 0; i < 4; i++)
    tile[ty + i * 8][tx] = in[(long)(r0 + ty + i * 8) * C + c0 + tx];
  __syncthreads();
#pragma unroll
  for (int i = 0; i < 4; i++)
    out[(long)(c0 + ty + i * 8) * R + r0 + tx] = f2bf(tile[tx][ty + i * 8]);
}

// ---------------------------------------------------------------------------
// Misc prep: embed+PE (0..2047), E->bf16 (2048..2431), qkv bias (2432..2503),
// fnp (2504..2505).
// ---------------------------------------------------------------------------
__global__ __launch_bounds__(256) void prep_misc(
    const int* __restrict__ x, const float* __restrict__ emb,
    const float* __restrict__ E,
    const float* __restrict__ bq, const float* __restrict__ bk,
    const float* __restrict__ bv,
    short* __restrict__ h, short* __restrict__ Ebf,
    float* __restrict__ qkvB, int* __restrict__ fnp) {
  const int z = blockIdx.x;
  const int tid = threadIdx.x;
  if (z < 2048) {
    const int s = z & 1023;
    const int xv = x[z];
    const int c = tid << 2;
    const float4 e = *(const float4*)(emb + (long)xv * 1024 + c);
    const float ev[4] = {e.x, e.y, e.z, e.w};
    s4_t o;
#pragma unroll
    for (int i = 0; i < 4; i++) {
      const int d = c + i;
      const float par = (float)(d & 1);
      const float rate = expf(-9.210340371976184f * (float)d / 1024.0f) *
                         expf(9.210340371976184f * par / 1024.0f);
      const float pe = sinf((float)s * rate + 1.5707963267948966f * par);
      o[i] = f2bf(ev[i] * 32.0f + pe);
    }
    *(s4_t*)(h + (long)z * 1024 + c) = o;
  } else if (z < 2432) {
    const long i = ((long)(z - 2048) * 256 + tid) * 4;
    const float4 t = *(const float4*)(E + i);
    s4_t o = {f2bf(t.x), f2bf(t.y), f2bf(t.z), f2bf(t.w)};
    *(s4_t*)(Ebf + i) = o;
  } else if (z < 2504) {
    const int idx = (z - 2432) * 256 + tid;
    const int l = idx / 3072, n = idx % 3072;
    float v = (n < 1024) ? bq[l * 1024 + n]
            : (n < 2048) ? bk[l * 1024 + n - 1024]
                         : bv[l * 1024 + n - 2048];
    qkvB[idx] = v;
  } else {
    if (tid < 64) {
      const int b = z - 2504;
      int first = 1024;
      for (int j0 = 0; j0 < 1024; j0 += 64) {
        unsigned long long m = __ballot(x[b * 1024 + j0 + tid] != 0);
        if (m) { first = j0 + __ffsll(m) - 1; break; }
      }
      if (tid == 0) fnp[b] = first;
    }
  }
}

// ---------------------------------------------------------------------------
// LayerNorm over D=1024, bf16 in/out. One block per row. In-place safe.
// ---------------------------------------------------------------------------
__global__ __launch_bounds__(256) void ln_kernel(const short* __restrict__ in,
                                                 short* __restrict__ out,
                                                 const float* __restrict__ g,
                                                 const float* __restrict__ be) {
  __shared__ float red[4];
  __shared__ float red2[4];
  const int row = blockIdx.x;
  const int tid = threadIdx.x;
  const int c = tid << 2;
  const s4_t xv = *(const s4_t*)(in + (long)row * 1024 + c);
  const float x0 = bf2f(xv[0]), x1 = bf2f(xv[1]), x2 = bf2f(xv[2]), x3 = bf2f(xv[3]);
  float s = x0 + x1 + x2 + x3;
#pragma unroll
  for (int off = 1; off < 64; off <<= 1) s += __shfl_xor(s, off);
  const int wave = tid >> 6, lane = tid & 63;
  if (lane == 0) red[wave] = s;
  __syncthreads();
  const float mu = (red[0] + red[1] + red[2] + red[3]) * (1.0f / 1024.0f);
  const float d0 = x0 - mu, d1 = x1 - mu, d2 = x2 - mu, d3 = x3 - mu;
  float q = d0 * d0 + d1 * d1 + d2 * d2 + d3 * d3;
#pragma unroll
  for (int off = 1; off < 64; off <<= 1) q += __shfl_xor(q, off);
  if (lane == 0) red2[wave] = q;
  __syncthreads();
  const float var = (red2[0] + red2[1] + red2[2] + red2[3]) * (1.0f / 1024.0f);
  const float rs = rsqrtf(var + 1e-6f);
  const float4 gv = *(const float4*)(g + c);
  const float4 bv = *(const float4*)(be + c);
  s4_t o = {f2bf(d0 * rs * gv.x + bv.x), f2bf(d1 * rs * gv.y + bv.y),
            f2bf(d2 * rs * gv.z + bv.z), f2bf(d3 * rs * gv.w + bv.w)};
  *(s4_t*)(out + (long)row * 1024 + c) = o;
}

// ---------------------------------------------------------------------------
// Generic MFMA GEMM: C[m][n] = sum_k A[m][k]*BT[n][k] (+bias) (+relu)
// ---------------------------------------------------------------------------
template <int BM, int BN, int WR, int WC, int OUT_BF16, int RELU>
__global__ __launch_bounds__(256) void gemm_lds(
    const short* __restrict__ A, const short* __restrict__ BT,
    void* __restrict__ Cv, const float* __restrict__ biasp,
    int K, int lda, int ldb, int ldc) {
  constexpr int AR = BM / 64, BR = BN / 64;
  constexpr int FI = BM / WR / 16, FJ = BN / WC / 16;
  __shared__ short As[BM * 32];
  __shared__ short Bs[BN * 32];
  const int bm = blockIdx.y * BM, bn = blockIdx.x * BN;
  const int tid = threadIdx.x;
  const int wave = tid >> 6, lane = tid & 63;
  const int quad = lane >> 4, l16 = lane & 15;
  const int wr = wave / WC, wc = wave % WC;
  const int wm = wr * (BM / WR), wn = wc * (BN / WC);

  const short* Ag = A + (long)(bm + wave * 16 + (lane >> 2)) * lda + ((lane & 3) << 3);
  const short* Bg = BT + (long)(bn + wave * 16 + (lane >> 2)) * ldb + ((lane & 3) << 3);

  f4v acc[FI][FJ];
#pragma unroll
  for (int i = 0; i < FI; i++)
#pragma unroll
    for (int j = 0; j < FJ; j++) {
      f4v zz = {0.f, 0.f, 0.f, 0.f};
      acc[i][j] = zz;
    }

  for (int k0 = 0; k0 < K; k0 += 32) {
#pragma unroll
    for (int r = 0; r < AR; r++)
      gld16(Ag + (long)r * 64 * lda + k0, As + r * 2048 + wave * 512);
#pragma unroll
    for (int r = 0; r < BR; r++)
      gld16(Bg + (long)r * 64 * ldb + k0, Bs + r * 2048 + wave * 512);
    __syncthreads();
    s8_t af[FI], bfr[FJ];
#pragma unroll
    for (int t = 0; t < FI; t++)
      af[t] = *(const s8_t*)&As[(wm + t * 16 + l16) * 32 + quad * 8];
#pragma unroll
    for (int t = 0; t < FJ; t++)
      bfr[t] = *(const s8_t*)&Bs[(wn + t * 16 + l16) * 32 + quad * 8];
#pragma unroll
    for (int ti = 0; ti < FI; ti++)
#pragma unroll
      for (int tj = 0; tj < FJ; tj++)
        acc[ti][tj] = mfma16(af[ti], bfr[tj], acc[ti][tj]);
    __syncthreads();
  }

#pragma unroll
  for (int ti = 0; ti < FI; ti++) {
#pragma unroll
    for (int tj = 0; tj < FJ; tj++) {
      const int n = bn + wn + tj * 16 + l16;
      const float bval = biasp ? biasp[n] : 0.f;
#pragma unroll
      for (int r = 0; r < 4; r++) {
        const int m = bm + wm + ti * 16 + quad * 4 + r;
        float vv = acc[ti][tj][r] + bval;
        if (RELU) vv = fmaxf(vv, 0.f);
        if (OUT_BF16) ((short*)Cv)[(long)m * ldc + n] = f2bf(vv);
        else          ((float*)Cv)[(long)m * ldc + n] = vv;
      }
    }
  }
}

// ---------------------------------------------------------------------------
// Attention with fused rel-pos. grid (B*H=32, 56). LDS 37.4 KB -> 4 blocks/CU.
// K fragments for QK^T read directly from global (L2-hot) — no K LDS stage.
// Barrier 1 (post-G) covers V-transpose + kneg; barrier 2 at loop end.
//  y in [0,40): split-j chunk path; itile<4 writes direct, else partials.
//  y in [40,56): pad-fallback (rows i<fnp fully masked -> unmasked attention).
// ---------------------------------------------------------------------------
__global__ __launch_bounds__(256, 4) void attn_main(
    const short* __restrict__ qkv, const short* __restrict__ Eb,
    const int* __restrict__ xids, const int* __restrict__ fnp,
    float* __restrict__ PO, float* __restrict__ PM, float* __restrict__ PL,
    short* __restrict__ outb) {
  __shared__ short Vt[64][136];      // [dim][key]
  __shared__ short Gs[4][16][152];   // per wave: G band (cols 0..143) then P (0..127)
  __shared__ float kneg[128];

  const int bh = blockIdx.x, b = bh >> 4, hh = bh & 15;
  const int yy = blockIdx.y;
  const bool fbp = (yy >= 40);
  const int itile = fbp ? (yy - 40) : IT_TAB[yy];
  const int cw = fbp ? 0 : CW_TAB[yy];
  const int fb = fnp[b];
  const int i0g = itile * 64;
  if (fbp && fb <= i0g) return;

  const int tid = threadIdx.x;
  const int wave = tid >> 6, lane = tid & 63, quad = lane >> 4, l16 = lane & 15;
  const int i0 = i0g + wave * 16;

  s8_t aq[2];
  {
    const short* qp = qkv + ((long)(b * 1024 + i0 + l16)) * 3072 + hh * 64 + quad * 8;
    aq[0] = *(const s8_t*)qp;
    aq[1] = *(const s8_t*)(qp + 32);
  }

  f4v o[4];
#pragma unroll
  for (int nt = 0; nt < 4; nt++) { f4v zz = {0.f, 0.f, 0.f, 0.f}; o[nt] = zz; }
  float m_run[4] = {-INFINITY, -INFINITY, -INFINITY, -INFINITY};
  float l_run[4] = {0.f, 0.f, 0.f, 0.f};

  const int half = wave >> 1;                  // V: dims half
  const int krow = ((wave & 1) << 6) + lane;   // V: key row within tile
  const short* kbase = qkv + (long)b * 1024 * 3072 + 1024 + hh * 64 + quad * 8;
  const short* vbase = qkv + (long)b * 1024 * 3072 + 2048 + hh * 64 + half * 32;
  short* gs = &Gs[wave][0][0];

  const int jBeg = fbp ? 0 : cw * 256;
  const int jEnd = fbp ? 1024 : min(cw * 256 + 256, i0g + 64);

  for (int j0 = jBeg; j0 < jEnd; j0 += 128) {
    // ---- V -> LDS transposed (clamped key index; overshoot keys masked) ----
    {
      const long kv = min(j0 + krow, 1023);
      const short* vrow = vbase + kv * 3072;
      const s8_t v0 = *(const s8_t*)(vrow);
      const s8_t v1 = *(const s8_t*)(vrow + 8);
      const s8_t v2 = *(const s8_t*)(vrow + 16);
      const s8_t v3 = *(const s8_t*)(vrow + 24);
#pragma unroll
      for (int t = 0; t < 8; t++) {
        Vt[half * 32 + t][krow] = v0[t];
        Vt[half * 32 + 8 + t][krow] = v1[t];
        Vt[half * 32 + 16 + t][krow] = v2[t];
        Vt[half * 32 + 24 + t][krow] = v3[t];
      }
    }
    if (tid < 128) kneg[tid] = (xids[b * 1024 + min(j0 + tid, 1023)] == 0) ? -1e9f : 0.0f;

    // ---- fused rel-pos band: G[row][col'] = q_(i0+row) . E_(mW+col') ----
    {
      const int mW = 1008 - i0g - wave * 16 + j0;
#pragma unroll
      for (int t = 0; t < 9; t++) {
        const int m = min(mW + t * 16 + l16, 1023);
        const short* ep = Eb + m * 64 + quad * 8;
        const s8_t eb0 = *(const s8_t*)ep;
        const s8_t eb1 = *(const s8_t*)(ep + 32);
        f4v g = {0.f, 0.f, 0.f, 0.f};
        g = mfma16(aq[0], eb0, g);
        g = mfma16(aq[1], eb1, g);
#pragma unroll
        for (int r = 0; r < 4; r++)
          gs[(quad * 4 + r) * 152 + t * 16 + l16] = f2bf(g[r]);
      }
    }
    __syncthreads();   // V + kneg visible to all waves

    // ---- scores 16x128: K frags straight from global (j <= 1023 always) ----
    float p[8][4];
    const int irow = i0 + quad * 4;
#pragma unroll
    for (int jt = 0; jt < 8; jt++) {
      const short* kf = kbase + (long)(j0 + jt * 16 + l16) * 3072;
      const s8_t k0f = *(const s8_t*)kf;
      const s8_t k1f = *(const s8_t*)(kf + 32);
      f4v zz = {0.f, 0.f, 0.f, 0.f};
      zz = mfma16(aq[0], k0f, zz);
      zz = mfma16(aq[1], k1f, zz);
      const int j = j0 + jt * 16 + l16;
      const float kn = kneg[jt * 16 + l16];
#pragma unroll
      for (int r = 0; r < 4; r++) {
        const int rr = quad * 4 + r;
        const float smv = bf2f(gs[rr * 151 + 15 + jt * 16 + l16]);
        const bool causal = (j <= irow + r);
        const float srel = causal ? smv : 0.f;
        const float kk = fbp ? 0.f : (causal ? kn : -1e9f);
        p[jt][r] = (zz[r] + srel) * 0.125f + kk;
      }
    }

    // ---- online softmax ----
    float alpha[4];
#pragma unroll
    for (int r = 0; r < 4; r++) {
      float mx = p[0][r];
#pragma unroll
      for (int jt = 1; jt < 8; jt++) mx = fmaxf(mx, p[jt][r]);
      mx = fmaxf(mx, __shfl_xor(mx, 1));
      mx = fmaxf(mx, __shfl_xor(mx, 2));
      mx = fmaxf(mx, __shfl_xor(mx, 4));
      mx = fmaxf(mx, __shfl_xor(mx, 8));
      const float mnew = fmaxf(m_run[r], mx);
      alpha[r] = expf(m_run[r] - mnew);
      float ps = 0.f;
#pragma unroll
      for (int jt = 0; jt < 8; jt++) {
        p[jt][r] = expf(p[jt][r] - mnew);
        ps += p[jt][r];
      }
      ps += __shfl_xor(ps, 1);
      ps += __shfl_xor(ps, 2);
      ps += __shfl_xor(ps, 4);
      ps += __shfl_xor(ps, 8);
      l_run[r] = l_run[r] * alpha[r] + ps;
      m_run[r] = mnew;
    }

    // ---- P -> LDS (A-layout, own wave region), rescale O ----
#pragma unroll
    for (int jt = 0; jt < 8; jt++)
#pragma unroll
      for (int r = 0; r < 4; r++)
        gs[(quad * 4 + r) * 152 + jt * 16 + l16] = f2bf(p[jt][r]);
#pragma unroll
    for (int nt = 0; nt < 4; nt++)
#pragma unroll
      for (int r = 0; r < 4; r++)
        o[nt][r] *= alpha[r];

    // ---- O += P @ V (K=128) ----
#pragma unroll
    for (int ks4 = 0; ks4 < 4; ks4++) {
      const s8_t ap = *(const s8_t*)&gs[l16 * 152 + ks4 * 32 + quad * 8];
#pragma unroll
      for (int nt = 0; nt < 4; nt++) {
        const s8_t vf = *(const s8_t*)&Vt[nt * 16 + l16][ks4 * 32 + quad * 8];
        o[nt] = mfma16(ap, vf, o[nt]);
      }
    }
    __syncthreads();   // protect Vt before next iteration's staging
  }

  // ---- epilogue ----
  if (fbp) {
#pragma unroll
    for (int nt = 0; nt < 4; nt++)
#pragma unroll
      for (int r = 0; r < 4; r++) {
        const int i = i0 + quad * 4 + r;
        if (i < fb)
          outb[((long)(b * 1024 + i)) * 1024 + hh * 64 + nt * 16 + l16] =
              f2bf(o[nt][r] / l_run[r]);
      }
  } else if (yy >= 36) {   // itile < 4: single chunk -> direct write
#pragma unroll
    for (int nt = 0; nt < 4; nt++)
#pragma unroll
      for (int r = 0; r < 4; r++) {
        const int i = i0 + quad * 4 + r;
        if (i >= fb)
          outb[((long)(b * 1024 + i)) * 1024 + hh * 64 + nt * 16 + l16] =
              f2bf(o[nt][r] / l_run[r]);
      }
  } else {
    const long part = (long)(bh * 16 + itile) * 4 + cw;
    float* po = PO + part * 4096;
#pragma unroll
    for (int nt = 0; nt < 4; nt++)
#pragma unroll
      for (int r = 0; r < 4; r++) {
        const int row = wave * 16 + quad * 4 + r;
        po[row * 64 + nt * 16 + l16] = o[nt][r];
      }
    if (l16 == 0) {
#pragma unroll
      for (int r = 0; r < 4; r++) {
        const int row = wave * 16 + quad * 4 + r;
        PM[part * 64 + row] = m_run[r];
        PL[part * 64 + row] = l_run[r];
      }
    }
  }
}

// combine partial chunks -> output for itile>=4. grid 384 (32 bh x 12), 256 thr.
__global__ __launch_bounds__(256) void attn_combine(
    const float* __restrict__ PO, const float* __restrict__ PM,
    const float* __restrict__ PL, const int* __restrict__ fnp,
    short* __restrict__ outb) {
  const int id = blockIdx.x;
  const int bh = id / 12, itile = 4 + id % 12;
  const int b = bh >> 4, hh = bh & 15;
  const int nc = (itile >> 2) + 1;
  const int row = threadIdx.x >> 2, seg = (threadIdx.x & 3) << 4;
  const long base = (long)(bh * 16 + itile) * 4;
  const int i = itile * 64 + row;
  if (i < fnp[b]) return;   // fully-masked rows handled by fallback path

  float mv[4];
  float M = -INFINITY;
  for (int c = 0; c < nc; c++) {
    mv[c] = PM[(base + c) * 64 + row];
    M = fmaxf(M, mv[c]);
  }
  f4v acc[4];
#pragma unroll
  for (int t = 0; t < 4; t++) { f4v zz = {0.f, 0.f, 0.f, 0.f}; acc[t] = zz; }
  float l = 0.f;
  for (int c = 0; c < nc; c++) {
    const float w = expf(mv[c] - M);
    l += w * PL[(base + c) * 64 + row];
    const float* po = PO + (base + c) * 4096 + row * 64 + seg;
#pragma unroll
    for (int t = 0; t < 4; t++) {
      const f4v v = *(const f4v*)(po + t * 4);
      acc[t] += w * v;
    }
  }
  const float inv = 1.0f / l;
  short* op = outb + ((long)(b * 1024 + i)) * 1024 + hh * 64 + seg;
#pragma unroll
  for (int t = 0; t < 4; t++) {
    s4_t o = {f2bf(acc[t][0] * inv), f2bf(acc[t][1] * inv),
              f2bf(acc[t][2] * inv), f2bf(acc[t][3] * inv)};
    *(s4_t*)(op + t * 4) = o;
  }
}

// ---------------------------------------------------------------------------
extern "C" void kernel_launch(void* const* d_in, const int* in_sizes, int n_in,
                              void* d_out, int out_size, void* d_ws, size_t ws_size,
                              hipStream_t stream) {
  const int*   x   = (const int*)d_in[0];
  const float* emb = (const float*)d_in[1];
  const float* Wq  = (const float*)d_in[2];
  const float* bq  = (const float*)d_in[3];
  const float* Wk  = (const float*)d_in[4];
  const float* bk  = (const float*)d_in[5];
  const float* Wv  = (const float*)d_in[6];
  const float* bv  = (const float*)d_in[7];
  const float* Wo  = (const float*)d_in[8];
  const float* bo  = (const float*)d_in[9];
  const float* W1  = (const float*)d_in[10];
  const float* b1  = (const float*)d_in[11];
  const float* W2  = (const float*)d_in[12];
  const float* b2  = (const float*)d_in[13];
  const float* g1  = (const float*)d_in[14];
  const float* be1 = (const float*)d_in[15];
  const float* g2  = (const float*)d_in[16];
  const float* be2 = (const float*)d_in[17];
  const float* E   = (const float*)d_in[18];
  const float* Wf  = (const float*)d_in[19];
  const float* bfv = (const float*)d_in[20];

  char* p = (char*)d_ws;
  auto alloc = [&](size_t bytes) {
    char* r = p;
    p += (bytes + 255) & ~(size_t)255;
    return r;
  };
  short* h    = (short*)alloc(2048ull * 1024 * 2);
  short* qkv  = (short*)alloc(2048ull * 3072 * 2);
  short* attn = (short*)alloc(2048ull * 1024 * 2);
  short* tmp  = (short*)alloc(2048ull * 1024 * 2);
  short* mid  = (short*)alloc(2048ull * 512 * 2);
  short* qkvT = (short*)alloc(6ull * 3072 * 1024 * 2);
  short* WoT  = (short*)alloc(6ull * 1024 * 1024 * 2);
  short* W1T  = (short*)alloc(6ull * 512 * 1024 * 2);
  short* W2T  = (short*)alloc(6ull * 1024 * 512 * 2);
  short* WfT  = (short*)alloc(256ull * 1024 * 2);
  short* Ebf  = (short*)alloc(6ull * 1024 * 64 * 2);
  float* qkvB = (float*)alloc(6ull * 3072 * 4);
  int*   fnp  = (int*)alloc(256);
  float* PO   = (float*)alloc(2048ull * 4096 * 4);
  float* PM   = (float*)alloc(2048ull * 64 * 4);
  float* PL   = (float*)alloc(2048ull * 64 * 4);

  prep_weights<<<30976, dim3(32, 8), 0, stream>>>(
      Wq, Wk, Wv, Wo, W1, W2, Wf, qkvT, WoT, W1T, W2T, WfT);
  prep_misc<<<2506, 256, 0, stream>>>(x, emb, E, bq, bk, bv, h, Ebf, qkvB, fnp);

  for (int l = 0; l < 6; l++) {
    const long wOff = (long)l * 1024 * 1024;
    const long w12Off = (long)l * 512 * 1024;
    gemm_lds<64, 128, 2, 2, 1, 0><<<dim3(24, 32), 256, 0, stream>>>(
        h, qkvT + (long)l * 3072 * 1024, qkv, qkvB + l * 3072, 1024, 1024, 1024, 3072);
    attn_main<<<dim3(32, 56), 256, 0, stream>>>(
        qkv, Ebf + (long)l * 1024 * 64, x, fnp, PO, PM, PL, attn);
    attn_combine<<<384, 256, 0, stream>>>(PO, PM, PL, fnp, attn);
    gemm_lds<64, 64, 2, 2, 1, 0><<<dim3(16, 32), 256, 0, stream>>>(
        attn, WoT + wOff, tmp, bo + l * 1024, 1024, 1024, 1024, 1024);
    ln_kernel<<<2048, 256, 0, stream>>>(tmp, tmp, g1 + l * 1024, be1 + l * 1024);
    gemm_lds<64, 64, 2, 2, 1, 1><<<dim3(8, 32), 256, 0, stream>>>(
        tmp, W1T + w12Off, mid, b1 + l * 512, 1024, 1024, 1024, 512);
    gemm_lds<64, 64, 2, 2, 1, 0><<<dim3(16, 32), 256, 0, stream>>>(
        mid, W2T + w12Off, h, b2 + l * 1024, 512, 512, 512, 1024);
    ln_kernel<<<2048, 256, 0, stream>>>(h, h, g2 + l * 1024, be2 + l * 1024);
  }
  gemm_lds<64, 64, 2, 2, 0, 0><<<dim3(4, 32), 256, 0, stream>>>(
      h, WfT, (float*)d_out, bfv, 1024, 1024, 1024, 256);
}